// Round 8
// baseline (173.396 us; speedup 1.0000x reference)
//
#include <hip/hip_runtime.h>
#include <math.h>

#define S_LEN 2048
#define E_DIM 1024
#define NHEAD 16
#define HD 64
#define WIN 128
#define NB 2
#define MTOT (NB * S_LEN)   // 4096
#define NMAT 3072

typedef float f32x4 __attribute__((ext_vector_type(4)));
typedef short bf16x8 __attribute__((ext_vector_type(8)));

#define GLOAD_LDS(g, l) __builtin_amdgcn_global_load_lds( \
    (const __attribute__((address_space(1))) unsigned int*)(g), \
    (__attribute__((address_space(3))) unsigned int*)(l), 16, 0, 0)

// LDS-only barrier: drains ds ops (cross-thread LDS visibility) but leaves
// plain global loads in flight across the barrier (unlike __syncthreads,
// which emits s_waitcnt vmcnt(0) and kills register prefetch).
#define BAR_LDS() do { asm volatile("s_waitcnt lgkmcnt(0)" ::: "memory"); \
                       __builtin_amdgcn_s_barrier(); } while (0)

__device__ __forceinline__ unsigned short f2bf(float f) {
    unsigned u = __float_as_uint(f);
    u += 0x7fffu + ((u >> 16) & 1u);   // RNE
    return (unsigned short)(u >> 16);
}
__device__ __forceinline__ float bf2f(unsigned short u) {
    return __uint_as_float(((unsigned)u) << 16);
}

// ---------------- fp32 -> bf16 conversion of x and concat(Wq,Wk,Wv) ----------------
__global__ __launch_bounds__(256) void convert_kernel(
    const float* __restrict__ x, const float* __restrict__ wq,
    const float* __restrict__ wk, const float* __restrict__ wv,
    unsigned short* __restrict__ xb, unsigned short* __restrict__ wb)
{
    const int NXQ = MTOT * E_DIM / 4;      // 1048576 quads
    const int NWQ = E_DIM * E_DIM / 4;     // 262144
    const int TOT = NXQ + 3 * NWQ;         // 1835008
    for (int i = blockIdx.x * 256 + threadIdx.x; i < TOT; i += gridDim.x * 256) {
        const float* src; unsigned short* dst; int off;
        if (i < NXQ)               { src = x;  dst = xb;                     off = i; }
        else if (i < NXQ + NWQ)    { src = wq; dst = wb;                     off = i - NXQ; }
        else if (i < NXQ + 2*NWQ)  { src = wk; dst = wb + E_DIM * E_DIM;     off = i - NXQ - NWQ; }
        else                       { src = wv; dst = wb + 2 * E_DIM * E_DIM; off = i - NXQ - 2*NWQ; }
        float4 v = ((const float4*)src)[off];
        ushort4 o;
        o.x = f2bf(v.x); o.y = f2bf(v.y); o.z = f2bf(v.z); o.w = f2bf(v.w);
        ((ushort4*)dst)[off] = o;
    }
}

// ---------------- bf16 MFMA GEMM: Y[m,n] = bias[n] + sum_k A[m,k]*B[n,k] ----------------
// Epilogue stores Q/K/V in the FAITHFUL reshape layout [bh][i][d]:
//   h = (m&2047)>>7, i = ((m&2047)&127)*16 + (n>>6), d = n&63   (reference view() w/o transpose)
__global__ __launch_bounds__(256) void gemm_mfma(
    const unsigned short* __restrict__ Ab, const unsigned short* __restrict__ Bb,
    const float* __restrict__ bq, const float* __restrict__ bk, const float* __restrict__ bv,
    unsigned short* __restrict__ Qb, unsigned short* __restrict__ Kb,
    unsigned short* __restrict__ Vb)
{
    __shared__ __align__(256) unsigned short As[128 * 64];
    __shared__ __align__(256) unsigned short Bs[128 * 64];
    const int tid  = threadIdx.x;
    const int lane = tid & 63;
    const int w    = tid >> 6;
    const int wm   = w & 1, wn = w >> 1;
    const int m0   = blockIdx.y * 128;
    const int n0   = blockIdx.x * 128;
    const int l15  = lane & 15, l4 = lane >> 4;

    f32x4 acc[16] = {};

    for (int k0 = 0; k0 < E_DIM; k0 += 64) {
        #pragma unroll
        for (int is = 0; is < 4; ++is) {
            int gid = is * 256 + tid;
            int r = gid >> 3, sl = gid & 7;
            int gran = sl ^ (r & 7);             // XOR swizzle (granule = 8 bf16 = 16 B)
            int wbs = is * 256 + (tid & 192);    // wave-uniform LDS base (granules)
            GLOAD_LDS(Ab + (size_t)(m0 + r) * E_DIM + k0 + gran * 8, As + wbs * 8);
            GLOAD_LDS(Bb + (size_t)(n0 + r) * E_DIM + k0 + gran * 8, Bs + wbs * 8);
        }
        __syncthreads();
        #pragma unroll
        for (int kk = 0; kk < 2; ++kk) {
            bf16x8 af[4], bfr[4];
            int sa = (kk * 4 + l4) ^ (l15 & 7);
            #pragma unroll
            for (int t = 0; t < 4; ++t) {
                int ra = wm * 64 + t * 16 + l15;
                af[t]  = *(const bf16x8*)&As[ra * 64 + sa * 8];
                int rb = wn * 64 + t * 16 + l15;
                bfr[t] = *(const bf16x8*)&Bs[rb * 64 + sa * 8];
            }
            #pragma unroll
            for (int mt = 0; mt < 4; ++mt)
                #pragma unroll
                for (int nt = 0; nt < 4; ++nt)
                    acc[mt * 4 + nt] = __builtin_amdgcn_mfma_f32_16x16x32_bf16(
                        af[mt], bfr[nt], acc[mt * 4 + nt], 0, 0, 0);
        }
        __syncthreads();
    }

    const int sel = n0 >> 10;
    const float* bias = (sel == 0) ? bq : ((sel == 1) ? bk : bv);
    unsigned short* Yb = (sel == 0) ? Qb : ((sel == 1) ? Kb : Vb);
    const int nbase = (n0 & 1023) + wn * 64;
    #pragma unroll
    for (int mt = 0; mt < 4; ++mt) {
        #pragma unroll
        for (int nt = 0; nt < 4; ++nt) {
            int n = nbase + nt * 16 + l15;      // e index in [0,1024)
            int c = n >> 6, d = n & 63;
            float bb = bias[n];
            #pragma unroll
            for (int r = 0; r < 4; ++r) {
                int m = m0 + wm * 64 + mt * 16 + l4 * 4 + r;
                int b = m >> 11, s = m & 2047;
                int h = s >> 7;
                int i = ((s & 127) << 4) + c;   // faithful reshape
                Yb[(((size_t)(b * 16 + h) * S_LEN + i) << 6) + d] =
                    f2bf(acc[mt * 4 + nt][r] + bb);
            }
        }
    }
}

// ---------------- vtot partials: vtp[seg][bh][d] = sum_{i in seg} V[bh][i][d] ----------------
__global__ __launch_bounds__(256) void vtot_part_kernel(
    const unsigned short* __restrict__ Vb, float* __restrict__ vtp)
{
    const int bh = blockIdx.x, seg = blockIdx.y;   // 32 x 8
    const int d = threadIdx.x & 63, sl = threadIdx.x >> 6;   // 4 i-slices of 64
    const unsigned short* p = Vb + ((size_t)bh * S_LEN + seg * 256 + sl * 64) * HD + d;
    float s = 0.f;
    #pragma unroll 8
    for (int j = 0; j < 64; ++j) s += bf2f(p[(size_t)j * HD]);
    __shared__ float red[4][64];
    red[sl][d] = s;
    __syncthreads();
    if (sl == 0)
        vtp[(seg * NB * NHEAD + bh) * HD + d] = red[0][d] + red[1][d] + red[2][d] + red[3][d];
}

// ---------------- MFMA attention: p'' = win ? e^{s*scale}-1 : 0 ----------------
// out = (sum p'' v + Vtot) / (sum p'' + S).
// 64-q tile (grid 1024 = 4 blocks/CU), register-prefetched K/V (plain loads stay
// in flight across raw barriers), single-buffered XOR-swizzled ks/vts, V
// transposed directly from registers.
__global__ __launch_bounds__(256) void attn_mfma(
    const unsigned short* __restrict__ Qb, const unsigned short* __restrict__ Kb,
    const unsigned short* __restrict__ Vb, const float* __restrict__ vtp,
    float* __restrict__ out)
{
    __shared__ __align__(256) unsigned short qs[64 * 64];
    __shared__ __align__(256) unsigned short ks[64 * 64];
    __shared__ __align__(256) unsigned short vts[64 * 64];
    __shared__ __align__(16)  unsigned short ps[4][16 * 72];   // per-wave P scratch

    const int qt = blockIdx.x, bh = blockIdx.y;
    const int b = bh >> 4, h = bh & 15;
    const int i0 = qt * 64;
    const int tid = threadIdx.x;
    const int w = tid >> 6, lane = tid & 63;
    const int l15 = lane & 15, quad = lane >> 4;

    // staging role: thread covers row lr, 16-bf16 segment lg
    const int lr = tid >> 2;        // 0..63
    const int lg = tid & 3;         // 0..3 -> d0 = lg*16
    const int d0 = lg * 16;
    const int keyr = lr & 7;
    const int g0 = lg * 2;          // first 8-elem granule of this segment
    const int oct = lr >> 3, jin = lr & 7;

    const unsigned short* Qp = Qb + (size_t)bh * S_LEN * HD;
    const unsigned short* Kp = Kb + (size_t)bh * S_LEN * HD;
    const unsigned short* Vp = Vb + (size_t)bh * S_LEN * HD;

    const int j_begin = (i0 - WIN > 0) ? i0 - WIN : 0;
    const int j_end   = (i0 + 64 + WIN < S_LEN) ? i0 + 64 + WIN : S_LEN;
    const int n_ch    = (j_end - j_begin) >> 6;   // 3..5

    // ---- issue loads: Q + chunks 0,1 (all rows in-bounds by construction) ----
    uint4 qlo = *(const uint4*)&Qp[(size_t)(i0 + lr) * HD + d0];
    uint4 qhi = *(const uint4*)&Qp[(size_t)(i0 + lr) * HD + d0 + 8];
    uint4 klo[2], khi[2], vlo[2], vhi[2];
    klo[0] = *(const uint4*)&Kp[(size_t)(j_begin + lr) * HD + d0];
    khi[0] = *(const uint4*)&Kp[(size_t)(j_begin + lr) * HD + d0 + 8];
    vlo[0] = *(const uint4*)&Vp[(size_t)(j_begin + lr) * HD + d0];
    vhi[0] = *(const uint4*)&Vp[(size_t)(j_begin + lr) * HD + d0 + 8];
    if (n_ch > 1) {
        klo[1] = *(const uint4*)&Kp[(size_t)(j_begin + 64 + lr) * HD + d0];
        khi[1] = *(const uint4*)&Kp[(size_t)(j_begin + 64 + lr) * HD + d0 + 8];
        vlo[1] = *(const uint4*)&Vp[(size_t)(j_begin + 64 + lr) * HD + d0];
        vhi[1] = *(const uint4*)&Vp[(size_t)(j_begin + 64 + lr) * HD + d0 + 8];
    }

    // ---- stage Q + chunk 0 into LDS ----
    *(uint4*)&qs[lr * 64 + (g0 ^ keyr) * 8]       = qlo;
    *(uint4*)&qs[lr * 64 + ((g0 + 1) ^ keyr) * 8] = qhi;
    *(uint4*)&ks[lr * 64 + (g0 ^ keyr) * 8]       = klo[0];
    *(uint4*)&ks[lr * 64 + ((g0 + 1) ^ keyr) * 8] = khi[0];
    {
        const unsigned short* plo = (const unsigned short*)&vlo[0];
        const unsigned short* phi = (const unsigned short*)&vhi[0];
        #pragma unroll
        for (int dd = 0; dd < 8; ++dd) {
            vts[(d0 + dd) * 64 + (oct ^ dd) * 8 + jin]     = plo[dd];
            vts[(d0 + 8 + dd) * 64 + (oct ^ dd) * 8 + jin] = phi[dd];
        }
    }
    BAR_LDS();

    // Q A-fragments: wave w owns q-rows w*16..w*16+15
    bf16x8 aq[2];
    {
        int row = w * 16 + l15;
        aq[0] = *(const bf16x8*)&qs[(row * 8 + (quad ^ (row & 7))) * 8];
        aq[1] = *(const bf16x8*)&qs[(row * 8 + ((4 + quad) ^ (row & 7))) * 8];
    }
    bf16x8 bones;
    #pragma unroll
    for (int t = 0; t < 8; ++t) bones[t] = (short)0x3F80;   // bf16 1.0

    f32x4 acc_o[4] = {};
    f32x4 acc_sum = {};
    unsigned short* psw = &ps[w][0];

    for (int c = 0; c < n_ch; ++c) {
        const int cb = c & 1;
        const int jc0 = j_begin + c * 64;

        if (c >= 1) {   // stage chunk c from regs (prev barrier protects reuse)
            *(uint4*)&ks[lr * 64 + (g0 ^ keyr) * 8]       = klo[cb];
            *(uint4*)&ks[lr * 64 + ((g0 + 1) ^ keyr) * 8] = khi[cb];
            const unsigned short* plo = (const unsigned short*)&vlo[cb];
            const unsigned short* phi = (const unsigned short*)&vhi[cb];
            #pragma unroll
            for (int dd = 0; dd < 8; ++dd) {
                vts[(d0 + dd) * 64 + (oct ^ dd) * 8 + jin]     = plo[dd];
                vts[(d0 + 8 + dd) * 64 + (oct ^ dd) * 8 + jin] = phi[dd];
            }
            BAR_LDS();
        }

        if (c + 2 < n_ch) {   // depth-2 prefetch into the freed register slot
            const int jn = j_begin + (c + 2) * 64 + lr;
            klo[cb] = *(const uint4*)&Kp[(size_t)jn * HD + d0];
            khi[cb] = *(const uint4*)&Kp[(size_t)jn * HD + d0 + 8];
            vlo[cb] = *(const uint4*)&Vp[(size_t)jn * HD + d0];
            vhi[cb] = *(const uint4*)&Vp[(size_t)jn * HD + d0 + 8];
        }

        // ---- QK^T: scores[16 q][64 j] ----
        f32x4 sacc[4] = {};
        #pragma unroll
        for (int kk = 0; kk < 2; ++kk) {
            #pragma unroll
            for (int jt = 0; jt < 4; ++jt) {
                int row = jt * 16 + l15;
                bf16x8 bk = *(const bf16x8*)&ks[(row * 8 + ((kk * 4 + quad) ^ (row & 7))) * 8];
                sacc[jt] = __builtin_amdgcn_mfma_f32_16x16x32_bf16(aq[kk], bk, sacc[jt], 0, 0, 0);
            }
        }

        // ---- p'' = in-window ? e^{s/8}-1 : 0 ; C-layout -> LDS -> A-layout (wave-local) ----
        #pragma unroll
        for (int jt = 0; jt < 4; ++jt) {
            int jg = jc0 + jt * 16 + l15;
            #pragma unroll
            for (int reg = 0; reg < 4; ++reg) {
                int i = i0 + w * 16 + quad * 4 + reg;
                bool valid = (jg >= i - WIN) && (jg < i + WIN);   // jg always in [0,S)
                float p = valid ? __expf(sacc[jt][reg] * 0.125f) - 1.f : 0.f;
                psw[(quad * 4 + reg) * 72 + jt * 16 + l15] = f2bf(p);
            }
        }
        bf16x8 ap0 = *(const bf16x8*)&psw[l15 * 72 + quad * 8];
        bf16x8 ap1 = *(const bf16x8*)&psw[l15 * 72 + 32 + quad * 8];

        // ---- PV + row-sum (ones trick) ----
        #pragma unroll
        for (int kst = 0; kst < 2; ++kst) {
            bf16x8 ap = kst ? ap1 : ap0;
            #pragma unroll
            for (int dt = 0; dt < 4; ++dt) {
                int row = dt * 16 + l15;
                bf16x8 bv_ = *(const bf16x8*)&vts[(row * 8 + ((kst * 4 + quad) ^ (row & 7))) * 8];
                acc_o[dt] = __builtin_amdgcn_mfma_f32_16x16x32_bf16(ap, bv_, acc_o[dt], 0, 0, 0);
            }
            acc_sum = __builtin_amdgcn_mfma_f32_16x16x32_bf16(ap, bones, acc_sum, 0, 0, 0);
        }

        if (c + 1 < n_ch) BAR_LDS();   // ks/vts reads done -> next iter may overwrite
    }

    // ---- epilogue (vtot = sum of 8 partials, L2-hot) ----
    float vtv[4];
    #pragma unroll
    for (int dt = 0; dt < 4; ++dt) {
        float s = 0.f;
        #pragma unroll
        for (int sg = 0; sg < 8; ++sg)
            s += vtp[(sg * NB * NHEAD + bh) * HD + dt * 16 + l15];
        vtv[dt] = s;
    }
    #pragma unroll
    for (int reg = 0; reg < 4; ++reg) {
        int i = i0 + w * 16 + quad * 4 + reg;
        float inv = 1.f / (acc_sum[reg] + (float)S_LEN);
        float* op = out + (((size_t)(b * S_LEN + i)) * NHEAD + h) * HD;
        #pragma unroll
        for (int dt = 0; dt < 4; ++dt)
            op[dt * 16 + l15] = (acc_o[dt][reg] + vtv[dt]) * inv;
    }
}

extern "C" void kernel_launch(void* const* d_in, const int* in_sizes, int n_in,
                              void* d_out, int out_size, void* d_ws, size_t ws_size,
                              hipStream_t stream)
{
    const float* x  = (const float*)d_in[0];
    const float* Wq = (const float*)d_in[1];
    const float* bq = (const float*)d_in[2];
    const float* Wk = (const float*)d_in[3];
    const float* bk = (const float*)d_in[4];
    const float* Wv = (const float*)d_in[5];
    const float* bv = (const float*)d_in[6];
    float* out = (float*)d_out;

    const size_t NY = (size_t)MTOT * E_DIM;   // 4194304 elements
    unsigned short* xb  = (unsigned short*)d_ws;
    unsigned short* wb  = xb + NY;                        // 3*E*E = 3145728
    unsigned short* Qb  = wb + (size_t)3 * E_DIM * E_DIM;
    unsigned short* Kb  = Qb + NY;
    unsigned short* Vb  = Kb + NY;
    float* vtp = (float*)(Vb + NY);                       // 8*32*64 fp32 partials

    convert_kernel<<<1792, 256, 0, stream>>>(x, Wq, Wk, Wv, xb, wb);
    gemm_mfma<<<dim3(NMAT / 128, MTOT / 128), 256, 0, stream>>>(xb, wb, bq, bk, bv, Qb, Kb, Vb);
    vtot_part_kernel<<<dim3(NB * NHEAD, 8), 256, 0, stream>>>(Vb, vtp);
    attn_mfma<<<dim3(S_LEN / 64, NB * NHEAD), 256, 0, stream>>>(Qb, Kb, Vb, vtp, out);
}

// Round 9
// 164.331 us; speedup vs baseline: 1.0552x; 1.0552x over previous
//
#include <hip/hip_runtime.h>
#include <math.h>

#define S_LEN 2048
#define E_DIM 1024
#define NHEAD 16
#define HD 64
#define WIN 128
#define NB 2
#define MTOT (NB * S_LEN)   // 4096
#define NMAT 3072

typedef float f32x4 __attribute__((ext_vector_type(4)));
typedef short bf16x8 __attribute__((ext_vector_type(8)));

#define GLOAD_LDS(g, l) __builtin_amdgcn_global_load_lds( \
    (const __attribute__((address_space(1))) unsigned int*)(g), \
    (__attribute__((address_space(3))) unsigned int*)(l), 16, 0, 0)

// LDS-only barrier: drains ds ops (cross-thread LDS visibility) but leaves
// plain global loads in flight across the barrier (unlike __syncthreads,
// which emits s_waitcnt vmcnt(0) and kills register prefetch).
#define BAR_LDS() do { asm volatile("s_waitcnt lgkmcnt(0)" ::: "memory"); \
                       __builtin_amdgcn_s_barrier(); } while (0)

__device__ __forceinline__ unsigned short f2bf(float f) {
    unsigned u = __float_as_uint(f);
    u += 0x7fffu + ((u >> 16) & 1u);   // RNE
    return (unsigned short)(u >> 16);
}
__device__ __forceinline__ float bf2f(unsigned short u) {
    return __uint_as_float(((unsigned)u) << 16);
}

// ---------------- fp32 -> bf16 conversion of x and concat(Wq,Wk,Wv) ----------------
__global__ __launch_bounds__(256) void convert_kernel(
    const float* __restrict__ x, const float* __restrict__ wq,
    const float* __restrict__ wk, const float* __restrict__ wv,
    unsigned short* __restrict__ xb, unsigned short* __restrict__ wb)
{
    const int NXQ = MTOT * E_DIM / 4;      // 1048576 quads
    const int NWQ = E_DIM * E_DIM / 4;     // 262144
    const int TOT = NXQ + 3 * NWQ;         // 1835008
    for (int i = blockIdx.x * 256 + threadIdx.x; i < TOT; i += gridDim.x * 256) {
        const float* src; unsigned short* dst; int off;
        if (i < NXQ)               { src = x;  dst = xb;                     off = i; }
        else if (i < NXQ + NWQ)    { src = wq; dst = wb;                     off = i - NXQ; }
        else if (i < NXQ + 2*NWQ)  { src = wk; dst = wb + E_DIM * E_DIM;     off = i - NXQ - NWQ; }
        else                       { src = wv; dst = wb + 2 * E_DIM * E_DIM; off = i - NXQ - 2*NWQ; }
        float4 v = ((const float4*)src)[off];
        ushort4 o;
        o.x = f2bf(v.x); o.y = f2bf(v.y); o.z = f2bf(v.z); o.w = f2bf(v.w);
        ((ushort4*)dst)[off] = o;
    }
}

// ---------------- bf16 MFMA GEMM: Y[m,n] = bias[n] + sum_k A[m,k]*B[n,k] ----------------
// Epilogue stores Q/K/V in the FAITHFUL reshape layout [bh][i][d]:
//   h = (m&2047)>>7, i = ((m&2047)&127)*16 + (n>>6), d = n&63   (reference view() w/o transpose)
__global__ __launch_bounds__(256) void gemm_mfma(
    const unsigned short* __restrict__ Ab, const unsigned short* __restrict__ Bb,
    const float* __restrict__ bq, const float* __restrict__ bk, const float* __restrict__ bv,
    unsigned short* __restrict__ Qb, unsigned short* __restrict__ Kb,
    unsigned short* __restrict__ Vb)
{
    __shared__ __align__(256) unsigned short As[128 * 64];
    __shared__ __align__(256) unsigned short Bs[128 * 64];
    const int tid  = threadIdx.x;
    const int lane = tid & 63;
    const int w    = tid >> 6;
    const int wm   = w & 1, wn = w >> 1;
    const int m0   = blockIdx.y * 128;
    const int n0   = blockIdx.x * 128;
    const int l15  = lane & 15, l4 = lane >> 4;

    f32x4 acc[16] = {};

    for (int k0 = 0; k0 < E_DIM; k0 += 64) {
        #pragma unroll
        for (int is = 0; is < 4; ++is) {
            int gid = is * 256 + tid;
            int r = gid >> 3, sl = gid & 7;
            int gran = sl ^ (r & 7);             // XOR swizzle (granule = 8 bf16 = 16 B)
            int wbs = is * 256 + (tid & 192);    // wave-uniform LDS base (granules)
            GLOAD_LDS(Ab + (size_t)(m0 + r) * E_DIM + k0 + gran * 8, As + wbs * 8);
            GLOAD_LDS(Bb + (size_t)(n0 + r) * E_DIM + k0 + gran * 8, Bs + wbs * 8);
        }
        __syncthreads();
        #pragma unroll
        for (int kk = 0; kk < 2; ++kk) {
            bf16x8 af[4], bfr[4];
            int sa = (kk * 4 + l4) ^ (l15 & 7);
            #pragma unroll
            for (int t = 0; t < 4; ++t) {
                int ra = wm * 64 + t * 16 + l15;
                af[t]  = *(const bf16x8*)&As[ra * 64 + sa * 8];
                int rb = wn * 64 + t * 16 + l15;
                bfr[t] = *(const bf16x8*)&Bs[rb * 64 + sa * 8];
            }
            #pragma unroll
            for (int mt = 0; mt < 4; ++mt)
                #pragma unroll
                for (int nt = 0; nt < 4; ++nt)
                    acc[mt * 4 + nt] = __builtin_amdgcn_mfma_f32_16x16x32_bf16(
                        af[mt], bfr[nt], acc[mt * 4 + nt], 0, 0, 0);
        }
        __syncthreads();
    }

    const int sel = n0 >> 10;
    const float* bias = (sel == 0) ? bq : ((sel == 1) ? bk : bv);
    unsigned short* Yb = (sel == 0) ? Qb : ((sel == 1) ? Kb : Vb);
    const int nbase = (n0 & 1023) + wn * 64;
    #pragma unroll
    for (int mt = 0; mt < 4; ++mt) {
        #pragma unroll
        for (int nt = 0; nt < 4; ++nt) {
            int n = nbase + nt * 16 + l15;      // e index in [0,1024)
            int c = n >> 6, d = n & 63;
            float bb = bias[n];
            #pragma unroll
            for (int r = 0; r < 4; ++r) {
                int m = m0 + wm * 64 + mt * 16 + l4 * 4 + r;
                int b = m >> 11, s = m & 2047;
                int h = s >> 7;
                int i = ((s & 127) << 4) + c;   // faithful reshape
                Yb[(((size_t)(b * 16 + h) * S_LEN + i) << 6) + d] =
                    f2bf(acc[mt * 4 + nt][r] + bb);
            }
        }
    }
}

// ---------------- vtot partials: vtp[seg][bh][d] = sum_{i in seg} V[bh][i][d] ----------------
__global__ __launch_bounds__(256) void vtot_part_kernel(
    const unsigned short* __restrict__ Vb, float* __restrict__ vtp)
{
    const int bh = blockIdx.x, seg = blockIdx.y;   // 32 x 8
    const int d = threadIdx.x & 63, sl = threadIdx.x >> 6;   // 4 i-slices of 64
    const unsigned short* p = Vb + ((size_t)bh * S_LEN + seg * 256 + sl * 64) * HD + d;
    float s = 0.f;
    #pragma unroll 8
    for (int j = 0; j < 64; ++j) s += bf2f(p[(size_t)j * HD]);
    __shared__ float red[4][64];
    red[sl][d] = s;
    __syncthreads();
    if (sl == 0)
        vtp[(seg * NB * NHEAD + bh) * HD + d] = red[0][d] + red[1][d] + red[2][d] + red[3][d];
}

// ---------------- MFMA attention: p'' = win ? e^{s*scale}-1 : 0 ----------------
// out = (sum p'' v + Vtot) / (sum p'' + S).
// 128-q tile, XCD-swizzled 1-D grid, register depth-2 prefetch (plain loads stay
// in flight across LDS-only barriers), double-buffered ks/vscr, two-stage
// conflict-free V transpose, 2 barriers/chunk.
__global__ __launch_bounds__(256) void attn_mfma(
    const unsigned short* __restrict__ Qb, const unsigned short* __restrict__ Kb,
    const unsigned short* __restrict__ Vb, const float* __restrict__ vtp,
    float* __restrict__ out)
{
    __shared__ __align__(256) unsigned short qs[128 * 64];      // 16 KB
    __shared__ __align__(256) unsigned short ks[2][64 * 64];    // 16 KB
    __shared__ __align__(256) unsigned short vscr[2][64 * 64];  // 16 KB (V rows)
    __shared__ __align__(256) unsigned short vts[64 * 64];      //  8 KB (V^T)
    __shared__ __align__(16)  unsigned short ps[4][32 * 72];    // 18 KB P scratch

    // XCD swizzle: blocks on XCD k (x%8==k) own 4 heads -> 3 MB/XCD fits L2
    const int x = blockIdx.x;
    const int bh = (x & 7) * 4 + (x >> 7);
    const int qt = (x >> 3) & 15;
    const int b = bh >> 4, h = bh & 15;
    const int i0 = qt * 128;
    const int tid = threadIdx.x;
    const int w = tid >> 6, lane = tid & 63;
    const int l15 = lane & 15, quad = lane >> 4;

    // staging role: thread covers row lr, 16-bf16 segment lg (granules g0,g0+1)
    const int lr = tid >> 2;
    const int lg = tid & 3;
    const int d0 = lg * 16;
    const int keyr = lr & 7;
    const int g0 = lg * 2;
    // transpose role
    const int td = tid & 63;
    const int toct = tid >> 6;

    const unsigned short* Qp = Qb + (size_t)bh * S_LEN * HD;
    const unsigned short* Kp = Kb + (size_t)bh * S_LEN * HD;
    const unsigned short* Vp = Vb + (size_t)bh * S_LEN * HD;

    const int j_begin = (i0 - WIN > 0) ? i0 - WIN : 0;
    const int j_end   = (i0 + 128 + WIN < S_LEN) ? i0 + 128 + WIN : S_LEN;
    const int n_ch    = (j_end - j_begin) >> 6;   // 4 (edges) or 6

    // ---- issue loads: Q (2 rows/thread) + chunks 0,1 ----
    uint4 q0lo = *(const uint4*)&Qp[(size_t)(i0 + lr) * HD + d0];
    uint4 q0hi = *(const uint4*)&Qp[(size_t)(i0 + lr) * HD + d0 + 8];
    uint4 q1lo = *(const uint4*)&Qp[(size_t)(i0 + 64 + lr) * HD + d0];
    uint4 q1hi = *(const uint4*)&Qp[(size_t)(i0 + 64 + lr) * HD + d0 + 8];
    uint4 klo[2], khi[2], vlo[2], vhi[2];
    #pragma unroll
    for (int sl2 = 0; sl2 < 2; ++sl2) {
        const int jr = j_begin + sl2 * 64 + lr;
        klo[sl2] = *(const uint4*)&Kp[(size_t)jr * HD + d0];
        khi[sl2] = *(const uint4*)&Kp[(size_t)jr * HD + d0 + 8];
        vlo[sl2] = *(const uint4*)&Vp[(size_t)jr * HD + d0];
        vhi[sl2] = *(const uint4*)&Vp[(size_t)jr * HD + d0 + 8];
    }

    // ---- stage Q + chunk 0 (coalesced b128, XOR-swizzled rows) ----
    *(uint4*)&qs[lr * 64 + (g0 ^ keyr) * 8]              = q0lo;
    *(uint4*)&qs[lr * 64 + ((g0 + 1) ^ keyr) * 8]        = q0hi;
    *(uint4*)&qs[(64 + lr) * 64 + (g0 ^ keyr) * 8]       = q1lo;
    *(uint4*)&qs[(64 + lr) * 64 + ((g0 + 1) ^ keyr) * 8] = q1hi;
    *(uint4*)&ks[0][lr * 64 + (g0 ^ keyr) * 8]           = klo[0];
    *(uint4*)&ks[0][lr * 64 + ((g0 + 1) ^ keyr) * 8]     = khi[0];
    *(uint4*)&vscr[0][lr * 64 + (g0 ^ keyr) * 8]         = vlo[0];
    *(uint4*)&vscr[0][lr * 64 + ((g0 + 1) ^ keyr) * 8]   = vhi[0];
    BAR_LDS();

    // Q A-fragments: wave w owns q rows w*32 .. w*32+31 (two 16-row subtiles)
    bf16x8 aq[2][2];
    #pragma unroll
    for (int q2 = 0; q2 < 2; ++q2) {
        int row = w * 32 + q2 * 16 + l15;
        aq[q2][0] = *(const bf16x8*)&qs[(row * 8 + (quad ^ (row & 7))) * 8];
        aq[q2][1] = *(const bf16x8*)&qs[(row * 8 + ((4 + quad) ^ (row & 7))) * 8];
    }
    bf16x8 bones;
    #pragma unroll
    for (int t = 0; t < 8; ++t) bones[t] = (short)0x3F80;   // bf16 1.0

    f32x4 acc_o[2][4] = {};
    f32x4 acc_sum[2] = {};
    unsigned short* psw = &ps[w][0];

    for (int c = 0; c < n_ch; ++c) {
        const int cb = c & 1;
        const int jc0 = j_begin + c * 64;

        // ---- in-LDS transpose: vscr[cb][j][d] -> vts[d][j] (conflict-free) ----
        #pragma unroll
        for (int pc = 0; pc < 2; ++pc) {
            int oct = toct + pc * 4;
            bf16x8 vv;
            #pragma unroll
            for (int t = 0; t < 8; ++t)
                vv[t] = (short)vscr[cb][(oct * 8 + t) * 64 + (((td >> 3) ^ t) * 8) + (td & 7)];
            *(bf16x8*)&vts[td * 64 + ((oct ^ (td & 7)) * 8)] = vv;
        }
        BAR_LDS();   // vts visible; prior chunk's ks/vscr[1-cb] reads all done

        if (c + 1 < n_ch) {   // stage chunk c+1 from regs into the other buffer
            *(uint4*)&ks[1 - cb][lr * 64 + (g0 ^ keyr) * 8]         = klo[1 - cb];
            *(uint4*)&ks[1 - cb][lr * 64 + ((g0 + 1) ^ keyr) * 8]   = khi[1 - cb];
            *(uint4*)&vscr[1 - cb][lr * 64 + (g0 ^ keyr) * 8]       = vlo[1 - cb];
            *(uint4*)&vscr[1 - cb][lr * 64 + ((g0 + 1) ^ keyr) * 8] = vhi[1 - cb];
        }
        if (c + 2 < n_ch) {   // depth-2 prefetch into the freed slot
            const int jr = j_begin + (c + 2) * 64 + lr;
            klo[cb] = *(const uint4*)&Kp[(size_t)jr * HD + d0];
            khi[cb] = *(const uint4*)&Kp[(size_t)jr * HD + d0 + 8];
            vlo[cb] = *(const uint4*)&Vp[(size_t)jr * HD + d0];
            vhi[cb] = *(const uint4*)&Vp[(size_t)jr * HD + d0 + 8];
        }

        // ---- QK^T: scores[2 x 16 q][64 j] ----
        f32x4 sacc[2][4] = {};
        const unsigned short* kb = ks[cb];
        #pragma unroll
        for (int kk = 0; kk < 2; ++kk) {
            #pragma unroll
            for (int jt = 0; jt < 4; ++jt) {
                int row = jt * 16 + l15;
                bf16x8 bk = *(const bf16x8*)&kb[(row * 8 + ((kk * 4 + quad) ^ (row & 7))) * 8];
                sacc[0][jt] = __builtin_amdgcn_mfma_f32_16x16x32_bf16(aq[0][kk], bk, sacc[0][jt], 0, 0, 0);
                sacc[1][jt] = __builtin_amdgcn_mfma_f32_16x16x32_bf16(aq[1][kk], bk, sacc[1][jt], 0, 0, 0);
            }
        }

        // ---- p'' = in-window ? e^{s/8}-1 : 0 ; C-layout -> LDS -> A-layout ----
        #pragma unroll
        for (int q2 = 0; q2 < 2; ++q2) {
            #pragma unroll
            for (int jt = 0; jt < 4; ++jt) {
                int jg = jc0 + jt * 16 + l15;
                #pragma unroll
                for (int reg = 0; reg < 4; ++reg) {
                    int i = i0 + w * 32 + q2 * 16 + quad * 4 + reg;
                    bool valid = (jg >= i - WIN) && (jg < i + WIN);   // jg always in [0,S)
                    float p = valid ? __expf(sacc[q2][jt][reg] * 0.125f) - 1.f : 0.f;
                    psw[(q2 * 16 + quad * 4 + reg) * 72 + jt * 16 + l15] = f2bf(p);
                }
            }
        }
        bf16x8 ap[2][2];
        #pragma unroll
        for (int q2 = 0; q2 < 2; ++q2) {
            ap[q2][0] = *(const bf16x8*)&psw[(q2 * 16 + l15) * 72 + quad * 8];
            ap[q2][1] = *(const bf16x8*)&psw[(q2 * 16 + l15) * 72 + 32 + quad * 8];
        }

        // ---- PV + row-sum (ones trick) ----
        #pragma unroll
        for (int kst = 0; kst < 2; ++kst) {
            #pragma unroll
            for (int dt = 0; dt < 4; ++dt) {
                int row = dt * 16 + l15;
                bf16x8 bv_ = *(const bf16x8*)&vts[(row * 8 + ((kst * 4 + quad) ^ (row & 7))) * 8];
                acc_o[0][dt] = __builtin_amdgcn_mfma_f32_16x16x32_bf16(ap[0][kst], bv_, acc_o[0][dt], 0, 0, 0);
                acc_o[1][dt] = __builtin_amdgcn_mfma_f32_16x16x32_bf16(ap[1][kst], bv_, acc_o[1][dt], 0, 0, 0);
            }
            acc_sum[0] = __builtin_amdgcn_mfma_f32_16x16x32_bf16(ap[0][kst], bones, acc_sum[0], 0, 0, 0);
            acc_sum[1] = __builtin_amdgcn_mfma_f32_16x16x32_bf16(ap[1][kst], bones, acc_sum[1], 0, 0, 0);
        }

        BAR_LDS();   // reads of ks[cb]/vts done; writes of ks/vscr[1-cb] drained
    }

    // ---- epilogue (vtot = sum of 8 partials, L2-hot) ----
    float vtv[4];
    #pragma unroll
    for (int dt = 0; dt < 4; ++dt) {
        float s = 0.f;
        #pragma unroll
        for (int sg = 0; sg < 8; ++sg)
            s += vtp[(sg * NB * NHEAD + bh) * HD + dt * 16 + l15];
        vtv[dt] = s;
    }
    #pragma unroll
    for (int q2 = 0; q2 < 2; ++q2) {
        #pragma unroll
        for (int reg = 0; reg < 4; ++reg) {
            int i = i0 + w * 32 + q2 * 16 + quad * 4 + reg;
            float inv = 1.f / (acc_sum[q2][reg] + (float)S_LEN);
            float* op = out + (((size_t)(b * S_LEN + i)) * NHEAD + h) * HD;
            #pragma unroll
            for (int dt = 0; dt < 4; ++dt)
                op[dt * 16 + l15] = (acc_o[q2][dt][reg] + vtv[dt]) * inv;
        }
    }
}

extern "C" void kernel_launch(void* const* d_in, const int* in_sizes, int n_in,
                              void* d_out, int out_size, void* d_ws, size_t ws_size,
                              hipStream_t stream)
{
    const float* x  = (const float*)d_in[0];
    const float* Wq = (const float*)d_in[1];
    const float* bq = (const float*)d_in[2];
    const float* Wk = (const float*)d_in[3];
    const float* bk = (const float*)d_in[4];
    const float* Wv = (const float*)d_in[5];
    const float* bv = (const float*)d_in[6];
    float* out = (float*)d_out;

    const size_t NY = (size_t)MTOT * E_DIM;   // 4194304 elements
    unsigned short* xb  = (unsigned short*)d_ws;
    unsigned short* wb  = xb + NY;                        // 3*E*E = 3145728
    unsigned short* Qb  = wb + (size_t)3 * E_DIM * E_DIM;
    unsigned short* Kb  = Qb + NY;
    unsigned short* Vb  = Kb + NY;
    float* vtp = (float*)(Vb + NY);                       // 8*32*64 fp32 partials

    convert_kernel<<<1792, 256, 0, stream>>>(x, Wq, Wk, Wv, xb, wb);
    gemm_mfma<<<dim3(NMAT / 128, MTOT / 128), 256, 0, stream>>>(xb, wb, bq, bk, bv, Qb, Kb, Vb);
    vtot_part_kernel<<<dim3(NB * NHEAD, 8), 256, 0, stream>>>(Vb, vtp);
    attn_mfma<<<512, 256, 0, stream>>>(Qb, Kb, Vb, vtp, out);
}